// Round 2
// baseline (308.435 us; speedup 1.0000x reference)
//
#include <hip/hip_runtime.h>

// OU Euler-Maruyama: x_{i+1} = a*x_i + b_i,  a = 1 - gamma*dt (per-chain const),
// b_i = gamma*mu*dt + sigma*sqrt(dt)*eps_i.
// Affine-map composition: per-lane 32-step local compose, 64-lane wave scan
// (shfl), sequential carry across 10 tiles within one wave.
// One wave per (n,m) chain: 2048 waves = 8 waves/CU.
// CHUNK=32 (vs 8 in R1): 4x fewer wave-scan rounds (the latency-bound part),
// 8 KB/wave in flight per prefetch. Tail: 20000-9*2048 = 1568 = 49 lanes*32.

#define T_STEPS 20000
#define M_PATHS 64
#define CHUNK   32           // elements per lane per tile
#define TILE    (64 * CHUNK) // 2048
#define NTILES  ((T_STEPS + TILE - 1) / TILE) // 10
#define DT      0.01f
#define SQRT_DT 0.1f

__global__ __launch_bounds__(256) void ou_scan_kernel(
    const float* __restrict__ theta,
    const float* __restrict__ noise,
    float* __restrict__ out)
{
    const int wave  = threadIdx.x >> 6;
    const int lane  = threadIdx.x & 63;
    const int chain = blockIdx.x * 4 + wave;      // 0 .. 2047
    const int n     = chain / M_PATHS;            // theta row

    const float gamma = theta[n * 4 + 0];
    const float mu    = theta[n * 4 + 1];
    const float sigma = theta[n * 4 + 2];
    float carry       = theta[n * 4 + 3];         // x_0

    const float a    = 1.0f - gamma * DT;
    const float gmdt = gamma * mu * DT;
    const float ssd  = sigma * SQRT_DT;
    const float a2  = a * a;
    const float a4  = a2 * a2;
    const float a8  = a4 * a4;
    const float a16 = a8 * a8;
    const float a32 = a16 * a16;

    const float* __restrict__ np_ = noise + (size_t)chain * T_STEPS;
    float* __restrict__       op_ = out   + (size_t)chain * T_STEPS;

    float4 cur[8], nxt[8];

    // ---- prefetch tile 0 ----
    {
        const int e0 = lane * CHUNK;
        const bool act = (e0 + CHUNK <= T_STEPS);
        #pragma unroll
        for (int k = 0; k < 8; ++k)
            cur[k] = act ? *(const float4*)(np_ + e0 + 4 * k)
                         : make_float4(0.f, 0.f, 0.f, 0.f);
    }

    for (int tb = 0; tb < NTILES; ++tb) {
        // ---- prefetch next tile (issued before current tile's compute) ----
        {
            const int ne0 = (tb + 1) * TILE + lane * CHUNK;
            const bool act = (tb + 1 < NTILES) && (ne0 + CHUNK <= T_STEPS);
            #pragma unroll
            for (int k = 0; k < 8; ++k)
                nxt[k] = act ? *(const float4*)(np_ + ne0 + 4 * k)
                             : make_float4(0.f, 0.f, 0.f, 0.f);
        }

        const int  base = tb * TILE + lane * CHUNK;
        const bool cact = (base + CHUNK <= T_STEPS);

        // local 32-step affine compose: x_out = a^32 * x_in + p
        // p starts at 0; p = a*p + b_j, b_j = gmdt + ssd*eps_j
        float p = 0.0f;
        #pragma unroll
        for (int k = 0; k < 8; ++k) {
            const float4 c = cur[k];
            p = fmaf(p, a, fmaf(ssd, c.x, gmdt));
            p = fmaf(p, a, fmaf(ssd, c.y, gmdt));
            p = fmaf(p, a, fmaf(ssd, c.z, gmdt));
            p = fmaf(p, a, fmaf(ssd, c.w, gmdt));
        }

        float A = cact ? a32 : 1.0f;  // inactive lanes: identity map
        float B = cact ? p   : 0.0f;

        // inclusive wave scan of affine maps (lane order = time order)
        #pragma unroll
        for (int d = 1; d < 64; d <<= 1) {
            const float pA = __shfl_up(A, d);
            const float pB = __shfl_up(B, d);
            if (lane >= d) {
                B = fmaf(A, pB, B);   // cur ∘ prev : A*(pA x + pB) + B
                A = A * pA;
            }
        }

        // exclusive prefix for this lane
        float Aex = __shfl_up(A, 1);
        float Bex = __shfl_up(B, 1);
        if (lane == 0) { Aex = 1.0f; Bex = 0.0f; }
        float x = fmaf(Aex, carry, Bex);   // state entering this lane's chunk

        // carry across tiles: lane 63's inclusive map applied to carry
        const float A63 = __shfl(A, 63);
        const float B63 = __shfl(B, 63);
        carry = fmaf(A63, carry, B63);

        if (cact) {
            #pragma unroll
            for (int k = 0; k < 8; ++k) {
                const float4 c = cur[k];
                float4 o;
                x = fmaf(a, x, fmaf(ssd, c.x, gmdt)); o.x = x;
                x = fmaf(a, x, fmaf(ssd, c.y, gmdt)); o.y = x;
                x = fmaf(a, x, fmaf(ssd, c.z, gmdt)); o.z = x;
                x = fmaf(a, x, fmaf(ssd, c.w, gmdt)); o.w = x;
                *(float4*)(op_ + base + 4 * k) = o;
            }
        }

        #pragma unroll
        for (int k = 0; k < 8; ++k) cur[k] = nxt[k];
    }
}

extern "C" void kernel_launch(void* const* d_in, const int* in_sizes, int n_in,
                              void* d_out, int out_size, void* d_ws, size_t ws_size,
                              hipStream_t stream) {
    const float* theta = (const float*)d_in[0];
    const float* noise = (const float*)d_in[1];
    float* out = (float*)d_out;

    const int chains = in_sizes[1] / T_STEPS;   // 2048
    const int blocks = chains / 4;              // 4 waves (chains) per 256-thr block
    ou_scan_kernel<<<blocks, 256, 0, stream>>>(theta, noise, out);
}